// Round 11
// baseline (509.941 us; speedup 1.0000x reference)
//
#include <hip/hip_runtime.h>
#include <cstdint>

constexpr int NN = 100000;   // nodes
constexpr int NE = 1600000;  // edges
constexpr int FIN = 512;
constexpr int HID = 128;
constexpr int NCLS = 6;
constexpr int EPAD = NE + 3 * NN;   // upper bound on pad-to-4 CSR edges

typedef __attribute__((ext_vector_type(8))) short short8v;  // 8 bf16 (4 VGPR)
typedef __attribute__((ext_vector_type(4))) float f32x4;

constexpr float WINV = 1.0f / 32767.0f;

__device__ __forceinline__ unsigned short f2bf(float f) {
    uint32_t u = __float_as_uint(f);
    uint32_t r = u + 0x7FFFu + ((u >> 16) & 1u);   // round-to-nearest-even
    return (unsigned short)(r >> 16);
}
__device__ __forceinline__ float bflo(uint32_t u) { return __uint_as_float(u << 16); }
__device__ __forceinline__ float bfhi(uint32_t u) { return __uint_as_float(u & 0xffff0000u); }

// async global -> LDS, 16B per lane; lds dest must be wave-uniform base
__device__ __forceinline__ void gl_lds16(const void* g, void* l) {
    __builtin_amdgcn_global_load_lds(
        (const __attribute__((address_space(1))) unsigned int*)(unsigned long long)g,
        (__attribute__((address_space(3))) unsigned int*)(unsigned int)(unsigned long long)l,
        16, 0, 0);
}

// ============ W1/W2/W3 fp32 -> fragment-ordered bf16, one launch ===========
__device__ __forceinline__ void cvt_body(const float* __restrict__ W,
                                         unsigned short* __restrict__ Bp, int t) {
    const int lane = t & 63;
    const int fi = t >> 6;
    const int n = fi & 7, ks = fi >> 3;
    const int krow = ks * 32 + (lane >> 4) * 8;
    const int col = n * 16 + (lane & 15);
    short8v sv;
    #pragma unroll
    for (int j = 0; j < 8; ++j) sv[j] = (short)f2bf(W[(size_t)(krow + j) * HID + col]);
    *(short8v*)&Bp[(size_t)t * 8] = sv;
}

__global__ void cvt_w3(const float* __restrict__ W1, const float* __restrict__ W2,
                       const float* __restrict__ W3,
                       unsigned short* __restrict__ Bp1, unsigned short* __restrict__ Bp2,
                       unsigned short* __restrict__ Bp3) {
    const int t = blockIdx.x * blockDim.x + threadIdx.x;
    constexpr int T1 = (FIN / 32) * 8 * 64;       // 8192
    constexpr int T2 = (HID / 32) * 8 * 64;       // 2048
    if (t < T1)                cvt_body(W1, Bp1, t);
    else if (t < T1 + T2)      cvt_body(W2, Bp2, t - T1);
    else if (t < T1 + 2 * T2)  cvt_body(W3, Bp3, t - T1 - T2);
}

// ============ LDS-staged MFMA GEMM: Sc[2][NN][64](bf16) = A[M,K] @ Bp ======
// BM=160 rows/block, 5 waves x 32 rows, KS=32. Per-wave private LDS slices,
// NO barriers. B frags loaded FIRST each step so one counted vmcnt(NISS)
// covers B + current A buffer while next-tile DMAs stay in flight (T4).
// Output half-split: chunk n -> half n>>2, offset (n&3)*16  (one 128B line
// per half-row, for the XCD-parity-pinned SpMM gathers).
template<int K, bool ABF>   // ABF: A is bf16 (else fp32)
__launch_bounds__(320)
__global__ void gemm_lds(const void* __restrict__ Av, const unsigned short* __restrict__ Bp,
                         unsigned short* __restrict__ Sc) {
    constexpr int BM    = 160;
    constexpr int KS    = 32;
    constexpr int EB    = ABF ? 2 : 4;       // element bytes
    constexpr int ROWB  = KS * EB;           // bytes per row window: 64 / 128
    constexpr int SLOTS = ROWB / 16;         // 4 / 8
    constexpr int SMSK  = SLOTS - 1;
    constexpr int CHUNK = BM * ROWB;         // 10240 / 20480
    constexpr int WBYT  = CHUNK / 5;         // bytes staged per wave: 2048 / 4096
    constexpr int NISS  = WBYT / 1024;       // DMA issues per wave per step: 2 / 4
    constexpr int NS    = K / KS;

    __shared__ __attribute__((aligned(16))) unsigned char lds[2 * CHUNK];

    const int tid  = threadIdx.x;
    const int lane = tid & 63;
    const int wave = tid >> 6;               // 0..4
    const int row0 = blockIdx.x * BM;
    const int lr   = lane & 15;
    const int kg   = lane >> 4;              // 0..3

    const unsigned char* Ab = (const unsigned char*)Av;
    const size_t rowbytes = (size_t)K * EB;

    // staging: per issue i, thread covers LDS byte Lw; src slot XOR-swizzled
    auto stage = [&](int bufsel, int ks) {
        const size_t kbyte = (size_t)ks * ROWB;
        #pragma unroll
        for (int i = 0; i < NISS; ++i) {
            const int Lw   = wave * WBYT + i * 1024 + lane * 16;
            const int row  = Lw / ROWB;
            const int slot = (Lw >> 4) & SMSK;
            const int src  = slot ^ (row & SMSK);
            const unsigned char* g = Ab + (size_t)(row0 + row) * rowbytes + kbyte + src * 16;
            void* l = (void*)&lds[bufsel * CHUNK + wave * WBYT + i * 1024];
            gl_lds16(g, l);
        }
    };

    f32x4 acc[2][8] = {};

    stage(0, 0);

    int cur = 0;
    for (int ks = 0; ks < NS; ++ks) {
        // ---- B fragments FIRST (so they're older than the stage DMAs) ----
        short8v bfr[8];
        const unsigned short* bb = Bp + ((size_t)ks * 8 * 64 + lane) * 8;
        #pragma unroll
        for (int n = 0; n < 8; ++n)
            bfr[n] = *reinterpret_cast<const short8v*>(bb + (size_t)n * 64 * 8);

        if (ks + 1 < NS) {
            stage(cur ^ 1, ks + 1);
            // drain everything except the NISS just-issued next-tile DMAs:
            // B frags of this step + current A buffer are then complete.
            asm volatile("s_waitcnt vmcnt(%0)" :: "i"(NISS) : "memory");
        } else {
            asm volatile("s_waitcnt vmcnt(0)" ::: "memory");
        }
        __builtin_amdgcn_sched_barrier(0);

        const unsigned char* base = &lds[cur * CHUNK];
        const int rA0 = wave * 32 + lr;
        const int rA1 = rA0 + 16;
        const int key = lr & SMSK;           // (rA0 & SMSK) == (rA1 & SMSK)

        short8v a0, a1;
        if constexpr (ABF) {
            a0 = *(const short8v*)(base + rA0 * ROWB + ((kg ^ key) * 16));
            a1 = *(const short8v*)(base + rA1 * ROWB + ((kg ^ key) * 16));
        } else {
            const float4 f00 = *(const float4*)(base + rA0 * ROWB + (((2 * kg + 0) ^ key) * 16));
            const float4 f01 = *(const float4*)(base + rA0 * ROWB + (((2 * kg + 1) ^ key) * 16));
            const float4 f10 = *(const float4*)(base + rA1 * ROWB + (((2 * kg + 0) ^ key) * 16));
            const float4 f11 = *(const float4*)(base + rA1 * ROWB + (((2 * kg + 1) ^ key) * 16));
            a0[0] = (short)f2bf(f00.x); a0[1] = (short)f2bf(f00.y);
            a0[2] = (short)f2bf(f00.z); a0[3] = (short)f2bf(f00.w);
            a0[4] = (short)f2bf(f01.x); a0[5] = (short)f2bf(f01.y);
            a0[6] = (short)f2bf(f01.z); a0[7] = (short)f2bf(f01.w);
            a1[0] = (short)f2bf(f10.x); a1[1] = (short)f2bf(f10.y);
            a1[2] = (short)f2bf(f10.z); a1[3] = (short)f2bf(f10.w);
            a1[4] = (short)f2bf(f11.x); a1[5] = (short)f2bf(f11.y);
            a1[6] = (short)f2bf(f11.z); a1[7] = (short)f2bf(f11.w);
        }

        #pragma unroll
        for (int n = 0; n < 8; ++n) {
            acc[0][n] = __builtin_amdgcn_mfma_f32_16x16x32_bf16(a0, bfr[n], acc[0][n], 0, 0, 0);
            acc[1][n] = __builtin_amdgcn_mfma_f32_16x16x32_bf16(a1, bfr[n], acc[1][n], 0, 0, 0);
        }
        cur ^= 1;
    }

    // half-split write: Sc[((n>>2)*NN + r)*64 + (n&3)*16 + lr]
    #pragma unroll
    for (int m = 0; m < 2; ++m)
        #pragma unroll
        for (int n = 0; n < 8; ++n)
            #pragma unroll
            for (int i = 0; i < 4; ++i) {
                const int r = row0 + wave * 32 + m * 16 + kg * 4 + i;
                Sc[((size_t)(n >> 2) * NN + r) * 64 + (n & 3) * 16 + lr] = f2bf(acc[m][n][i]);
            }
}

// ---------------- GEMM for W4 [128,6], bf16 H ------------------------------
__global__ void gemm_w4(const unsigned short* __restrict__ H, const float* __restrict__ W,
                        float* __restrict__ S, int M) {
    __shared__ float Ws[HID * NCLS];
    for (int i = threadIdx.x; i < HID * NCLS; i += blockDim.x) Ws[i] = W[i];
    __syncthreads();
    const int r = blockIdx.x * blockDim.x + threadIdx.x;
    if (r >= M) return;
    float acc[NCLS] = {};
    const unsigned short* h = &H[(size_t)r * HID];
    for (int k0 = 0; k0 < HID; k0 += 8) {
        const uint4 hv = *reinterpret_cast<const uint4*>(&h[k0]);
        float hf[8];
        hf[0] = bflo(hv.x); hf[1] = bfhi(hv.x);
        hf[2] = bflo(hv.y); hf[3] = bfhi(hv.y);
        hf[4] = bflo(hv.z); hf[5] = bfhi(hv.z);
        hf[6] = bflo(hv.w); hf[7] = bfhi(hv.w);
        #pragma unroll
        for (int u = 0; u < 8; ++u)
            #pragma unroll
            for (int j = 0; j < NCLS; ++j)
                acc[j] = fmaf(hf[u], Ws[(k0 + u) * NCLS + j], acc[j]);
    }
    #pragma unroll
    for (int j = 0; j < NCLS; ++j) S[(size_t)r * NCLS + j] = acc[j];
}

// ================= CSR construction (rows padded to %4, packed 4B edges) ===
// edge word = (col << 15) | round(w * 32767)
__global__ void hist_k(const int4* __restrict__ erow4, int* __restrict__ cnt) {
    const int t = blockIdx.x * blockDim.x + threadIdx.x;
    if (t >= NE / 4) return;
    const int4 r = erow4[t];
    atomicAdd(&cnt[r.x], 1);
    atomicAdd(&cnt[r.y], 1);
    atomicAdd(&cnt[r.z], 1);
    atomicAdd(&cnt[r.w], 1);
}

__global__ void scan1_k(const int* __restrict__ in, int* __restrict__ out,
                        int* __restrict__ bsum, int n) {
    __shared__ int s[256];
    const int tid = threadIdx.x;
    const int gid = blockIdx.x * 256 + tid;
    const int v = (gid < NN) ? ((in[gid] + 3) & ~3) : 0;
    s[tid] = v;
    __syncthreads();
    for (int off = 1; off < 256; off <<= 1) {
        const int t = (tid >= off) ? s[tid - off] : 0;
        __syncthreads();
        s[tid] += t;
        __syncthreads();
    }
    if (gid < n) out[gid] = s[tid] - v;
    if (tid == 255) bsum[blockIdx.x] = s[255];
}

__global__ void scan2_k(int* __restrict__ bsum, int nb) {
    __shared__ int s[512];
    const int tid = threadIdx.x;
    const int v = (tid < nb) ? bsum[tid] : 0;
    s[tid] = v;
    __syncthreads();
    for (int off = 1; off < 512; off <<= 1) {
        const int t = (tid >= off) ? s[tid - off] : 0;
        __syncthreads();
        s[tid] += t;
        __syncthreads();
    }
    if (tid < nb) bsum[tid] = s[tid] - v;
}

__global__ void scan3_k(int* __restrict__ out, const int* __restrict__ bsum, int n) {
    const int gid = blockIdx.x * 256 + threadIdx.x;
    if (gid < n) out[gid] += bsum[blockIdx.x];
}

__global__ void scatter_k(const int4* __restrict__ erow4, const int4* __restrict__ ecol4,
                          const float4* __restrict__ ew4,
                          const int* __restrict__ row_ptr, int* __restrict__ cur,
                          uint32_t* __restrict__ edges) {
    const int t = blockIdx.x * blockDim.x + threadIdx.x;
    if (t >= NE / 4) return;
    const int4 r = erow4[t];
    const int4 c = ecol4[t];
    const float4 w = ew4[t];
    {
        const int pos = row_ptr[r.x] + atomicAdd(&cur[r.x], 1);
        edges[pos] = ((uint32_t)c.x << 15) | (uint32_t)(w.x * 32767.0f + 0.5f);
    }
    {
        const int pos = row_ptr[r.y] + atomicAdd(&cur[r.y], 1);
        edges[pos] = ((uint32_t)c.y << 15) | (uint32_t)(w.y * 32767.0f + 0.5f);
    }
    {
        const int pos = row_ptr[r.z] + atomicAdd(&cur[r.z], 1);
        edges[pos] = ((uint32_t)c.z << 15) | (uint32_t)(w.z * 32767.0f + 0.5f);
    }
    {
        const int pos = row_ptr[r.w] + atomicAdd(&cur[r.w], 1);
        edges[pos] = ((uint32_t)c.w << 15) | (uint32_t)(w.w * 32767.0f + 0.5f);
    }
}

// zero only the pad slots (cnt[r]..row_ptr[r+1])
__global__ void pad_k(const int* __restrict__ row_ptr, const int* __restrict__ cur,
                      uint32_t* __restrict__ edges) {
    const int r = blockIdx.x * blockDim.x + threadIdx.x;
    if (r >= NN) return;
    const int end = row_ptr[r + 1];
    for (int p = row_ptr[r] + cur[r]; p < end; ++p) edges[p] = 0u;
}

// ============ CSR SpMM, F=128, half-split XCD-parity-pinned ================
// Sc[2][NN][64] bf16: a half-row = ONE 128B line (full-line gathers, no
// waste). half = blockIdx.x & 1; XCD = blockIdx % 8 -> even XCDs serve half 0,
// odd XCDs half 1 -> per-XCD gather working set 12.8MB (vs 25.6).
// 64 lanes = 64 feats (1 ushort/lane). 4 rows/block per half. 16-deep MLP.
template<bool RELU>
__launch_bounds__(256)
__global__ void spmm_half(const int* __restrict__ row_ptr,
                          const uint32_t* __restrict__ edges,
                          const unsigned short* __restrict__ Sc,
                          const float* __restrict__ bias,
                          unsigned short* __restrict__ out) {
    const int lane = threadIdx.x & 63;
    const int half = blockIdx.x & 1;
    const int row = (blockIdx.x >> 1) * 4 + (threadIdx.x >> 6);
    if (row >= NN) return;
    const int beg = row_ptr[row];
    const int end = row_ptr[row + 1];
    const unsigned short* S = Sc + (size_t)half * NN * 64 + lane;

    float a0 = bias[half * 64 + lane];
    float a1 = 0.f, a2 = 0.f, a3 = 0.f;

    int j = beg;
    // main: 16 edges/iter, 16 independent 2B gathers (128B/wave each)
    for (; j + 16 <= end; j += 16) {
        uint4 e0 = *reinterpret_cast<const uint4*>(edges + j);
        uint4 e1 = *reinterpret_cast<const uint4*>(edges + j + 4);
        uint4 e2 = *reinterpret_cast<const uint4*>(edges + j + 8);
        uint4 e3 = *reinterpret_cast<const uint4*>(edges + j + 12);
        const uint32_t ea[16] = {e0.x, e0.y, e0.z, e0.w, e1.x, e1.y, e1.z, e1.w,
                                 e2.x, e2.y, e2.z, e2.w, e3.x, e3.y, e3.z, e3.w};
        uint32_t s[16];
        #pragma unroll
        for (int q = 0; q < 16; ++q)
            s[q] = (uint32_t)S[(size_t)(ea[q] >> 15) * 64];
        #pragma unroll
        for (int q = 0; q < 4; ++q) {
            const float w0 = (float)(ea[q]      & 0x7FFFu) * WINV;
            const float w1 = (float)(ea[q + 4]  & 0x7FFFu) * WINV;
            const float w2 = (float)(ea[q + 8]  & 0x7FFFu) * WINV;
            const float w3 = (float)(ea[q + 12] & 0x7FFFu) * WINV;
            a0 = fmaf(bflo(s[q] << 16),      w0 * 65536.f, a0 * 1.f),  // placeholder avoided below
            a0 = a0;  // (see real FMAs below)
            // real accumulation:
            a0 = fmaf(bflo(s[q]),      w0, a0);
            a1 = fmaf(bflo(s[q + 4]),  w1, a1);
            a2 = fmaf(bflo(s[q + 8]),  w2, a2);
            a3 = fmaf(bflo(s[q + 12]), w3, a3);
        }
    }
    // tail: 4 edges/iter (rows padded to %4)
    for (; j < end; j += 4) {
        const uint4 e = *reinterpret_cast<const uint4*>(edges + j);
        const uint32_t ea[4] = {e.x, e.y, e.z, e.w};
        uint32_t s[4];
        #pragma unroll
        for (int q = 0; q < 4; ++q)
            s[q] = (uint32_t)S[(size_t)(ea[q] >> 15) * 64];
        a0 = fmaf(bflo(s[0]), (float)(ea[0] & 0x7FFFu) * WINV, a0);
        a1 = fmaf(bflo(s[1]), (float)(ea[1] & 0x7FFFu) * WINV, a1);
        a2 = fmaf(bflo(s[2]), (float)(ea[2] & 0x7FFFu) * WINV, a2);
        a3 = fmaf(bflo(s[3]), (float)(ea[3] & 0x7FFFu) * WINV, a3);
    }
    float f = (a0 + a1) + (a2 + a3);
    if (RELU) f = fmaxf(f, 0.f);
    out[(size_t)row * HID + half * 64 + lane] = f2bf(f);
}

// ============ CSR SpMM, F=6, fp32, 16 lanes/row ============================
__launch_bounds__(256)
__global__ void spmm6(const int* __restrict__ row_ptr,
                      const uint32_t* __restrict__ edges,
                      const float* __restrict__ S,
                      const float* __restrict__ bias,
                      float* __restrict__ out) {
    const int t = blockIdx.x * blockDim.x + threadIdx.x;
    const int row = t >> 4;
    const int sl = t & 15;
    if (row >= NN) return;
    const int beg = row_ptr[row];
    const int end = row_ptr[row + 1];
    float acc[NCLS] = {};
    for (int j = beg + sl; j < end; j += 16) {
        const uint32_t e = edges[j];
        const float w = (float)(e & 0x7FFFu) * WINV;
        const float* s = &S[(size_t)(e >> 15) * NCLS];
        #pragma unroll
        for (int k = 0; k < NCLS; ++k) acc[k] = fmaf(s[k], w, acc[k]);
    }
    #pragma unroll
    for (int off = 8; off > 0; off >>= 1)
        #pragma unroll
        for (int k = 0; k < NCLS; ++k) acc[k] += __shfl_xor(acc[k], off, 64);
    if (sl == 0) {
        #pragma unroll
        for (int k = 0; k < NCLS; ++k) out[(size_t)row * NCLS + k] = acc[k] + bias[k];
    }
}

extern "C" void kernel_launch(void* const* d_in, const int* in_sizes, int n_in,
                              void* d_out, int out_size, void* d_ws, size_t ws_size,
                              hipStream_t stream) {
    const float* x    = (const float*)d_in[0];
    const int*   erow = (const int*)d_in[1];
    const int*   ecol = (const int*)d_in[2];
    const float* ew   = (const float*)d_in[3];
    const float* W1 = (const float*)d_in[4];  const float* b1 = (const float*)d_in[5];
    const float* W2 = (const float*)d_in[6];  const float* b2 = (const float*)d_in[7];
    const float* W3 = (const float*)d_in[8];  const float* b3 = (const float*)d_in[9];
    const float* W4 = (const float*)d_in[10]; const float* b4 = (const float*)d_in[11];
    float* out = (float*)d_out;

    // ---- workspace layout ----
    uint32_t*       edges_s = (uint32_t*)d_ws;                      // EPAD*4B
    unsigned short* sup16   = (unsigned short*)(edges_s + EPAD);    // [2][NN][64] bf16
    unsigned short* h16     = sup16 + (size_t)NN * HID;             // NN*128*2B (row-major)
    float*          sup6    = (float*)(h16 + (size_t)NN * HID);     // NN*6*4B
    unsigned short* Bp1     = (unsigned short*)(sup6 + (size_t)NN * NCLS);
    unsigned short* Bp2     = Bp1 + (size_t)FIN * HID;
    unsigned short* Bp3     = Bp2 + (size_t)HID * HID;
    int*            row_ptr = (int*)(Bp3 + (size_t)HID * HID);      // NN+1
    int*            row_cnt = row_ptr + (NN + 1);                   // NN (hist)
    int*            row_cur = row_cnt + NN;                         // NN (scatter cursor)
    int*            bsum    = row_cur + NN;                         // 512

    const dim3 blk(256);
    const int  g_edge4 = (NE / 4 + 255) / 256;
    const int  NB = (NN + 1 + 255) / 256;

    // ---- weights -> fragment-ordered bf16 ----
    cvt_w3<<<(12288 + 255) / 256, blk, 0, stream>>>(W1, W2, W3, Bp1, Bp2, Bp3);

    // ---- build CSR (rows padded to %4; packed 4B edges; int4 reads) ----
    hipMemsetAsync(row_cnt, 0, (size_t)2 * NN * sizeof(int), stream);  // cnt + cur
    hist_k<<<g_edge4, blk, 0, stream>>>((const int4*)erow, row_cnt);
    scan1_k<<<NB, blk, 0, stream>>>(row_cnt, row_ptr, bsum, NN + 1);
    scan2_k<<<1, 512, 0, stream>>>(bsum, NB);
    scan3_k<<<NB, blk, 0, stream>>>(row_ptr, bsum, NN + 1);
    scatter_k<<<g_edge4, blk, 0, stream>>>((const int4*)erow, (const int4*)ecol,
                                           (const float4*)ew, row_ptr, row_cur, edges_s);
    pad_k<<<(NN + 255) / 256, blk, 0, stream>>>(row_ptr, row_cur, edges_s);

    const int g_gemm = NN / 160;            // 625, exact
    const int g_spmm = 2 * ((NN + 3) / 4);  // 50000: half = bid & 1

    // ---- layer 1 ----
    gemm_lds<FIN, false><<<g_gemm, dim3(320), 0, stream>>>(x, Bp1, sup16);
    spmm_half<true><<<g_spmm, blk, 0, stream>>>(row_ptr, edges_s, sup16, b1, h16);
    // ---- layer 2 ----
    gemm_lds<HID, true><<<g_gemm, dim3(320), 0, stream>>>(h16, Bp2, sup16);
    spmm_half<true><<<g_spmm, blk, 0, stream>>>(row_ptr, edges_s, sup16, b2, h16);
    // ---- layer 3 ----
    gemm_lds<HID, true><<<g_gemm, dim3(320), 0, stream>>>(h16, Bp3, sup16);
    spmm_half<true><<<g_spmm, blk, 0, stream>>>(row_ptr, edges_s, sup16, b3, h16);
    // ---- layer 4 ----
    gemm_w4<<<(NN + 255) / 256, blk, 0, stream>>>(h16, W4, sup6, NN);
    spmm6<<<(NN * 16 + 255) / 256, blk, 0, stream>>>(row_ptr, edges_s, sup6, b4, out);
}

// Round 12
// 418.517 us; speedup vs baseline: 1.2184x; 1.2184x over previous
//
#include <hip/hip_runtime.h>
#include <cstdint>

constexpr int NN = 100000;   // nodes
constexpr int NE = 1600000;  // edges
constexpr int FIN = 512;
constexpr int HID = 128;
constexpr int NCLS = 6;
constexpr int EPAD = NE + 3 * NN;   // upper bound on pad-to-4 CSR edges

typedef __attribute__((ext_vector_type(8))) short short8v;  // 8 bf16 (4 VGPR)
typedef __attribute__((ext_vector_type(4))) float f32x4;

constexpr float WINV = 1.0f / 32767.0f;

__device__ __forceinline__ unsigned short f2bf(float f) {
    uint32_t u = __float_as_uint(f);
    uint32_t r = u + 0x7FFFu + ((u >> 16) & 1u);   // round-to-nearest-even
    return (unsigned short)(r >> 16);
}
__device__ __forceinline__ float bflo(uint32_t u) { return __uint_as_float(u << 16); }
__device__ __forceinline__ float bfhi(uint32_t u) { return __uint_as_float(u & 0xffff0000u); }

// async global -> LDS, 16B per lane; lds dest must be wave-uniform base
__device__ __forceinline__ void gl_lds16(const void* g, void* l) {
    __builtin_amdgcn_global_load_lds(
        (const __attribute__((address_space(1))) unsigned int*)(unsigned long long)g,
        (__attribute__((address_space(3))) unsigned int*)(unsigned int)(unsigned long long)l,
        16, 0, 0);
}

// ============ W fp32 -> fragment-ordered bf16 (device body) ================
__device__ __forceinline__ void cvt_body(const float* __restrict__ W,
                                         unsigned short* __restrict__ Bp, int t) {
    const int lane = t & 63;
    const int fi = t >> 6;
    const int n = fi & 7, ks = fi >> 3;
    const int krow = ks * 32 + (lane >> 4) * 8;
    const int col = n * 16 + (lane & 15);
    short8v sv;
    #pragma unroll
    for (int j = 0; j < 8; ++j) sv[j] = (short)f2bf(W[(size_t)(krow + j) * HID + col]);
    *(short8v*)&Bp[(size_t)t * 8] = sv;
}

// ============ GEMM body: C[r][128](bf16) = A[tile,K] @ Bp ==================
// BM=160 rows, 5 waves x 32 rows, KS=32. Per-wave private LDS slices, NO
// barriers. B frags loaded FIRST each step; one counted vmcnt(NISS) keeps
// next-tile DMAs in flight (T4). lds must hold 2*BM*KS*EB bytes.
template<int K, bool ABF>
__device__ __forceinline__ void gemm_body(unsigned char* lds,
                                          const void* __restrict__ Av,
                                          const unsigned short* __restrict__ Bp,
                                          unsigned short* __restrict__ C, int bid) {
    constexpr int BM    = 160;
    constexpr int KS    = 32;
    constexpr int EB    = ABF ? 2 : 4;
    constexpr int ROWB  = KS * EB;           // 64 / 128
    constexpr int SLOTS = ROWB / 16;         // 4 / 8
    constexpr int SMSK  = SLOTS - 1;
    constexpr int CHUNK = BM * ROWB;         // 10240 / 20480
    constexpr int WBYT  = CHUNK / 5;
    constexpr int NISS  = WBYT / 1024;       // 2 / 4
    constexpr int NS    = K / KS;

    const int tid  = threadIdx.x;
    const int lane = tid & 63;
    const int wave = tid >> 6;               // 0..4
    const int row0 = bid * BM;
    const int lr   = lane & 15;
    const int kg   = lane >> 4;              // 0..3

    const unsigned char* Ab = (const unsigned char*)Av;
    const size_t rowbytes = (size_t)K * EB;

    auto stage = [&](int bufsel, int ks) {
        const size_t kbyte = (size_t)ks * ROWB;
        #pragma unroll
        for (int i = 0; i < NISS; ++i) {
            const int Lw   = wave * WBYT + i * 1024 + lane * 16;
            const int row  = Lw / ROWB;
            const int slot = (Lw >> 4) & SMSK;
            const int src  = slot ^ (row & SMSK);
            const unsigned char* g = Ab + (size_t)(row0 + row) * rowbytes + kbyte + src * 16;
            void* l = (void*)&lds[bufsel * CHUNK + wave * WBYT + i * 1024];
            gl_lds16(g, l);
        }
    };

    f32x4 acc[2][8] = {};

    stage(0, 0);

    int cur = 0;
    for (int ks = 0; ks < NS; ++ks) {
        short8v bfr[8];
        const unsigned short* bb = Bp + ((size_t)ks * 8 * 64 + lane) * 8;
        #pragma unroll
        for (int n = 0; n < 8; ++n)
            bfr[n] = *reinterpret_cast<const short8v*>(bb + (size_t)n * 64 * 8);

        if (ks + 1 < NS) {
            stage(cur ^ 1, ks + 1);
            asm volatile("s_waitcnt vmcnt(%0)" :: "i"(NISS) : "memory");
        } else {
            asm volatile("s_waitcnt vmcnt(0)" ::: "memory");
        }
        __builtin_amdgcn_sched_barrier(0);

        const unsigned char* base = &lds[cur * CHUNK];
        const int rA0 = wave * 32 + lr;
        const int rA1 = rA0 + 16;
        const int key = lr & SMSK;

        short8v a0, a1;
        if constexpr (ABF) {
            a0 = *(const short8v*)(base + rA0 * ROWB + ((kg ^ key) * 16));
            a1 = *(const short8v*)(base + rA1 * ROWB + ((kg ^ key) * 16));
        } else {
            const float4 f00 = *(const float4*)(base + rA0 * ROWB + (((2 * kg + 0) ^ key) * 16));
            const float4 f01 = *(const float4*)(base + rA0 * ROWB + (((2 * kg + 1) ^ key) * 16));
            const float4 f10 = *(const float4*)(base + rA1 * ROWB + (((2 * kg + 0) ^ key) * 16));
            const float4 f11 = *(const float4*)(base + rA1 * ROWB + (((2 * kg + 1) ^ key) * 16));
            a0[0] = (short)f2bf(f00.x); a0[1] = (short)f2bf(f00.y);
            a0[2] = (short)f2bf(f00.z); a0[3] = (short)f2bf(f00.w);
            a0[4] = (short)f2bf(f01.x); a0[5] = (short)f2bf(f01.y);
            a0[6] = (short)f2bf(f01.z); a0[7] = (short)f2bf(f01.w);
            a1[0] = (short)f2bf(f10.x); a1[1] = (short)f2bf(f10.y);
            a1[2] = (short)f2bf(f10.z); a1[3] = (short)f2bf(f10.w);
            a1[4] = (short)f2bf(f11.x); a1[5] = (short)f2bf(f11.y);
            a1[6] = (short)f2bf(f11.z); a1[7] = (short)f2bf(f11.w);
        }

        #pragma unroll
        for (int n = 0; n < 8; ++n) {
            acc[0][n] = __builtin_amdgcn_mfma_f32_16x16x32_bf16(a0, bfr[n], acc[0][n], 0, 0, 0);
            acc[1][n] = __builtin_amdgcn_mfma_f32_16x16x32_bf16(a1, bfr[n], acc[1][n], 0, 0, 0);
        }
        cur ^= 1;
    }

    // C/D layout: col = lane&15, row = (lane>>4)*4 + reg   [m89-verified]
    #pragma unroll
    for (int m = 0; m < 2; ++m)
        #pragma unroll
        for (int n = 0; n < 8; ++n)
            #pragma unroll
            for (int i = 0; i < 4; ++i) {
                const int r = row0 + wave * 32 + m * 16 + kg * 4 + i;
                C[(size_t)r * HID + n * 16 + lr] = f2bf(acc[m][n][i]);
            }
}

// ---- standalone GEMM kernel (layers 2/3, bf16 A) --------------------------
__launch_bounds__(320)
__global__ void gemm_lds_bf(const void* __restrict__ Av, const unsigned short* __restrict__ Bp,
                            unsigned short* __restrict__ C) {
    __shared__ __attribute__((aligned(16))) unsigned char lds[2 * 160 * 64];
    gemm_body<HID, true>(lds, Av, Bp, C, blockIdx.x);
}

// ============ scatter / pad device bodies ==================================
__device__ __forceinline__ void scatter_one(int r, int c, float w,
                                            const int* __restrict__ row_ptr,
                                            int* __restrict__ cur,
                                            uint32_t* __restrict__ edges) {
    const int pos = row_ptr[r] + atomicAdd(&cur[r], 1);
    edges[pos] = ((uint32_t)c << 15) | (uint32_t)(w * 32767.0f + 0.5f);
}

// ============ FUSED: hist + cvt_w3 (independent work, one launch) ==========
__global__ void fused_hist_cvt(const int4* __restrict__ erow4, int* __restrict__ cnt,
                               const float* __restrict__ W1, const float* __restrict__ W2,
                               const float* __restrict__ W3,
                               unsigned short* __restrict__ Bp1, unsigned short* __restrict__ Bp2,
                               unsigned short* __restrict__ Bp3) {
    constexpr int NB_HIST = (NE / 4 + 255) / 256;     // 1563
    const int bid = blockIdx.x;
    if (bid < NB_HIST) {
        const int t = bid * 256 + threadIdx.x;
        if (t < NE / 4) {
            const int4 r = erow4[t];
            atomicAdd(&cnt[r.x], 1);
            atomicAdd(&cnt[r.y], 1);
            atomicAdd(&cnt[r.z], 1);
            atomicAdd(&cnt[r.w], 1);
        }
    } else {
        const int t = (bid - NB_HIST) * 256 + threadIdx.x;
        constexpr int T1 = (FIN / 32) * 8 * 64;       // 8192
        constexpr int T2 = (HID / 32) * 8 * 64;       // 2048
        if (t < T1)                cvt_body(W1, Bp1, t);
        else if (t < T1 + T2)      cvt_body(W2, Bp2, t - T1);
        else if (t < T1 + 2 * T2)  cvt_body(W3, Bp3, t - T1 - T2);
    }
}

// ============ FUSED: layer-1 GEMM + scatter + pad ==========================
// pad uses row_cnt (final hist counts) so its slots are DISJOINT from
// scatter's -> safe concurrency. All independent of gemm's outputs.
constexpr int GB_GEMM = NN / 160;                          // 625
constexpr int GB_SCAT = (NE / 4 + 319) / 320;              // 1250
constexpr int GB_PAD  = (NN + 319) / 320;                  // 313

__launch_bounds__(320)
__global__ void fused_l1(const float* __restrict__ x, const unsigned short* __restrict__ Bp1,
                         unsigned short* __restrict__ sup16,
                         const int4* __restrict__ erow4, const int4* __restrict__ ecol4,
                         const float4* __restrict__ ew4,
                         const int* __restrict__ row_ptr, const int* __restrict__ row_cnt,
                         int* __restrict__ cur, uint32_t* __restrict__ edges) {
    __shared__ __attribute__((aligned(16))) unsigned char lds[2 * 160 * 128];
    const int bid = blockIdx.x;
    if (bid < GB_GEMM) {
        gemm_body<FIN, false>(lds, x, Bp1, sup16, bid);
    } else if (bid < GB_GEMM + GB_SCAT) {
        const int t = (bid - GB_GEMM) * 320 + threadIdx.x;
        if (t < NE / 4) {
            const int4 r = erow4[t];
            const int4 c = ecol4[t];
            const float4 w = ew4[t];
            scatter_one(r.x, c.x, w.x, row_ptr, cur, edges);
            scatter_one(r.y, c.y, w.y, row_ptr, cur, edges);
            scatter_one(r.z, c.z, w.z, row_ptr, cur, edges);
            scatter_one(r.w, c.w, w.w, row_ptr, cur, edges);
        }
    } else {
        const int r = (bid - GB_GEMM - GB_SCAT) * 320 + threadIdx.x;
        if (r < NN) {
            const int end = row_ptr[r + 1];
            for (int p = row_ptr[r] + row_cnt[r]; p < end; ++p) edges[p] = 0u;
        }
    }
}

// ---------------- GEMM for W4 [128,6], bf16 H ------------------------------
__global__ void gemm_w4(const unsigned short* __restrict__ H, const float* __restrict__ W,
                        float* __restrict__ S, int M) {
    __shared__ float Ws[HID * NCLS];
    for (int i = threadIdx.x; i < HID * NCLS; i += blockDim.x) Ws[i] = W[i];
    __syncthreads();
    const int r = blockIdx.x * blockDim.x + threadIdx.x;
    if (r >= M) return;
    float acc[NCLS] = {};
    const unsigned short* h = &H[(size_t)r * HID];
    for (int k0 = 0; k0 < HID; k0 += 8) {
        const uint4 hv = *reinterpret_cast<const uint4*>(&h[k0]);
        float hf[8];
        hf[0] = bflo(hv.x); hf[1] = bfhi(hv.x);
        hf[2] = bflo(hv.y); hf[3] = bfhi(hv.y);
        hf[4] = bflo(hv.z); hf[5] = bfhi(hv.z);
        hf[6] = bflo(hv.w); hf[7] = bfhi(hv.w);
        #pragma unroll
        for (int u = 0; u < 8; ++u)
            #pragma unroll
            for (int j = 0; j < NCLS; ++j)
                acc[j] = fmaf(hf[u], Ws[(k0 + u) * NCLS + j], acc[j]);
    }
    #pragma unroll
    for (int j = 0; j < NCLS; ++j) S[(size_t)r * NCLS + j] = acc[j];
}

// ================= scans (pad counts to %4) ================================
__global__ void scan1_k(const int* __restrict__ in, int* __restrict__ out,
                        int* __restrict__ bsum, int n) {
    __shared__ int s[256];
    const int tid = threadIdx.x;
    const int gid = blockIdx.x * 256 + tid;
    const int v = (gid < NN) ? ((in[gid] + 3) & ~3) : 0;
    s[tid] = v;
    __syncthreads();
    for (int off = 1; off < 256; off <<= 1) {
        const int t = (tid >= off) ? s[tid - off] : 0;
        __syncthreads();
        s[tid] += t;
        __syncthreads();
    }
    if (gid < n) out[gid] = s[tid] - v;
    if (tid == 255) bsum[blockIdx.x] = s[255];
}

__global__ void scan2_k(int* __restrict__ bsum, int nb) {
    __shared__ int s[512];
    const int tid = threadIdx.x;
    const int v = (tid < nb) ? bsum[tid] : 0;
    s[tid] = v;
    __syncthreads();
    for (int off = 1; off < 512; off <<= 1) {
        const int t = (tid >= off) ? s[tid - off] : 0;
        __syncthreads();
        s[tid] += t;
        __syncthreads();
    }
    if (tid < nb) bsum[tid] = s[tid] - v;
}

__global__ void scan3_k(int* __restrict__ out, const int* __restrict__ bsum, int n) {
    const int gid = blockIdx.x * 256 + threadIdx.x;
    if (gid < n) out[gid] += bsum[blockIdx.x];
}

// ============ CSR SpMM, F=128, bf16 in/out, 16-deep gather MLP =============
// 64 lanes per row: each edge gather = 256B contiguous (full S row).
template<bool RELU>
__launch_bounds__(256)
__global__ void spmm_bf16(const int* __restrict__ row_ptr,
                          const uint32_t* __restrict__ edges,
                          const unsigned short* __restrict__ S,
                          const float* __restrict__ bias,
                          unsigned short* __restrict__ out) {
    const int lane = threadIdx.x & 63;
    const int row = blockIdx.x * 4 + (threadIdx.x >> 6);
    if (row >= NN) return;
    const int beg = row_ptr[row];
    const int end = row_ptr[row + 1];
    const int fo = lane * 2;
    float2 a0 = *reinterpret_cast<const float2*>(&bias[fo]);
    float2 a1 = {0.f, 0.f}, a2 = {0.f, 0.f}, a3 = {0.f, 0.f};

    int j = beg;
    for (; j + 16 <= end; j += 16) {
        uint4 e0 = *reinterpret_cast<const uint4*>(edges + j);
        uint4 e1 = *reinterpret_cast<const uint4*>(edges + j + 4);
        uint4 e2 = *reinterpret_cast<const uint4*>(edges + j + 8);
        uint4 e3 = *reinterpret_cast<const uint4*>(edges + j + 12);
        const uint32_t ea[16] = {e0.x, e0.y, e0.z, e0.w, e1.x, e1.y, e1.z, e1.w,
                                 e2.x, e2.y, e2.z, e2.w, e3.x, e3.y, e3.z, e3.w};
        uint32_t s[16];
        #pragma unroll
        for (int q = 0; q < 16; ++q)
            s[q] = *reinterpret_cast<const uint32_t*>(&S[(size_t)(ea[q] >> 15) * HID + fo]);
        #pragma unroll
        for (int q = 0; q < 4; ++q) {
            const float w0 = (float)(ea[q]      & 0x7FFFu) * WINV;
            const float w1 = (float)(ea[q + 4]  & 0x7FFFu) * WINV;
            const float w2 = (float)(ea[q + 8]  & 0x7FFFu) * WINV;
            const float w3 = (float)(ea[q + 12] & 0x7FFFu) * WINV;
            a0.x = fmaf(bflo(s[q]),      w0, a0.x); a0.y = fmaf(bfhi(s[q]),      w0, a0.y);
            a1.x = fmaf(bflo(s[q + 4]),  w1, a1.x); a1.y = fmaf(bfhi(s[q + 4]),  w1, a1.y);
            a2.x = fmaf(bflo(s[q + 8]),  w2, a2.x); a2.y = fmaf(bfhi(s[q + 8]),  w2, a2.y);
            a3.x = fmaf(bflo(s[q + 12]), w3, a3.x); a3.y = fmaf(bfhi(s[q + 12]), w3, a3.y);
        }
    }
    for (; j < end; j += 4) {
        const uint4 e = *reinterpret_cast<const uint4*>(edges + j);
        const uint32_t ea[4] = {e.x, e.y, e.z, e.w};
        uint32_t s[4];
        #pragma unroll
        for (int q = 0; q < 4; ++q)
            s[q] = *reinterpret_cast<const uint32_t*>(&S[(size_t)(ea[q] >> 15) * HID + fo]);
        const float w0 = (float)(ea[0] & 0x7FFFu) * WINV;
        const float w1 = (float)(ea[1] & 0x7FFFu) * WINV;
        const float w2 = (float)(ea[2] & 0x7FFFu) * WINV;
        const float w3 = (float)(ea[3] & 0x7FFFu) * WINV;
        a0.x = fmaf(bflo(s[0]), w0, a0.x); a0.y = fmaf(bfhi(s[0]), w0, a0.y);
        a1.x = fmaf(bflo(s[1]), w1, a1.x); a1.y = fmaf(bfhi(s[1]), w1, a1.y);
        a2.x = fmaf(bflo(s[2]), w2, a2.x); a2.y = fmaf(bfhi(s[2]), w2, a2.y);
        a3.x = fmaf(bflo(s[3]), w3, a3.x); a3.y = fmaf(bfhi(s[3]), w3, a3.y);
    }
    float fx = (a0.x + a1.x) + (a2.x + a3.x);
    float fy = (a0.y + a1.y) + (a2.y + a3.y);
    if (RELU) { fx = fmaxf(fx, 0.f); fy = fmaxf(fy, 0.f); }
    const uint32_t o = (uint32_t)f2bf(fx) | ((uint32_t)f2bf(fy) << 16);
    *reinterpret_cast<uint32_t*>(&out[(size_t)row * HID + fo]) = o;
}

// ============ CSR SpMM, F=6, fp32, 16 lanes/row ============================
__launch_bounds__(256)
__global__ void spmm6(const int* __restrict__ row_ptr,
                      const uint32_t* __restrict__ edges,
                      const float* __restrict__ S,
                      const float* __restrict__ bias,
                      float* __restrict__ out) {
    const int t = blockIdx.x * blockDim.x + threadIdx.x;
    const int row = t >> 4;
    const int sl = t & 15;
    if (row >= NN) return;
    const int beg = row_ptr[row];
    const int end = row_ptr[row + 1];
    float acc[NCLS] = {};
    for (int j = beg + sl; j < end; j += 16) {
        const uint32_t e = edges[j];
        const float w = (float)(e & 0x7FFFu) * WINV;
        const float* s = &S[(size_t)(e >> 15) * NCLS];
        #pragma unroll
        for (int k = 0; k < NCLS; ++k) acc[k] = fmaf(s[k], w, acc[k]);
    }
    #pragma unroll
    for (int off = 8; off > 0; off >>= 1)
        #pragma unroll
        for (int k = 0; k < NCLS; ++k) acc[k] += __shfl_xor(acc[k], off, 64);
    if (sl == 0) {
        #pragma unroll
        for (int k = 0; k < NCLS; ++k) out[(size_t)row * NCLS + k] = acc[k] + bias[k];
    }
}

extern "C" void kernel_launch(void* const* d_in, const int* in_sizes, int n_in,
                              void* d_out, int out_size, void* d_ws, size_t ws_size,
                              hipStream_t stream) {
    const float* x    = (const float*)d_in[0];
    const int*   erow = (const int*)d_in[1];
    const int*   ecol = (const int*)d_in[2];
    const float* ew   = (const float*)d_in[3];
    const float* W1 = (const float*)d_in[4];  const float* b1 = (const float*)d_in[5];
    const float* W2 = (const float*)d_in[6];  const float* b2 = (const float*)d_in[7];
    const float* W3 = (const float*)d_in[8];  const float* b3 = (const float*)d_in[9];
    const float* W4 = (const float*)d_in[10]; const float* b4 = (const float*)d_in[11];
    float* out = (float*)d_out;

    // ---- workspace layout ----
    uint32_t*       edges_s = (uint32_t*)d_ws;                      // EPAD*4B
    unsigned short* sup16   = (unsigned short*)(edges_s + EPAD);    // NN*128*2B
    unsigned short* h16     = sup16 + (size_t)NN * HID;             // NN*128*2B
    float*          sup6    = (float*)(h16 + (size_t)NN * HID);     // NN*6*4B
    unsigned short* Bp1     = (unsigned short*)(sup6 + (size_t)NN * NCLS);
    unsigned short* Bp2     = Bp1 + (size_t)FIN * HID;
    unsigned short* Bp3     = Bp2 + (size_t)HID * HID;
    int*            row_ptr = (int*)(Bp3 + (size_t)HID * HID);      // NN+1
    int*            row_cnt = row_ptr + (NN + 1);                   // NN (hist)
    int*            row_cur = row_cnt + NN;                         // NN (scatter cursor)
    int*            bsum    = row_cur + NN;                         // 512

    const dim3 blk(256);
    const int  NB = (NN + 1 + 255) / 256;
    constexpr int NB_HIST = (NE / 4 + 255) / 256;                   // 1563
    constexpr int NB_CVT  = 12288 / 256;                            // 48

    // ---- memset cnt+cur, then fused hist + weight-convert ----
    hipMemsetAsync(row_cnt, 0, (size_t)2 * NN * sizeof(int), stream);
    fused_hist_cvt<<<NB_HIST + NB_CVT, blk, 0, stream>>>(
        (const int4*)erow, row_cnt, W1, W2, W3, Bp1, Bp2, Bp3);

    // ---- scan (pad counts to %4) ----
    scan1_k<<<NB, blk, 0, stream>>>(row_cnt, row_ptr, bsum, NN + 1);
    scan2_k<<<1, 512, 0, stream>>>(bsum, NB);
    scan3_k<<<NB, blk, 0, stream>>>(row_ptr, bsum, NN + 1);

    // ---- FUSED layer-1 GEMM + edge scatter + pad (disjoint slots) ----
    fused_l1<<<GB_GEMM + GB_SCAT + GB_PAD, dim3(320), 0, stream>>>(
        x, Bp1, sup16, (const int4*)erow, (const int4*)ecol, (const float4*)ew,
        row_ptr, row_cnt, row_cur, edges_s);

    const int g_spmm = NN / 4;
    // ---- layer 1 aggregate ----
    spmm_bf16<true><<<g_spmm, blk, 0, stream>>>(row_ptr, edges_s, sup16, b1, h16);
    // ---- layer 2 ----
    gemm_lds_bf<<<GB_GEMM, dim3(320), 0, stream>>>(h16, Bp2, sup16);
    spmm_bf16<true><<<g_spmm, blk, 0, stream>>>(row_ptr, edges_s, sup16, b2, h16);
    // ---- layer 3 ----
    gemm_lds_bf<<<GB_GEMM, dim3(320), 0, stream>>>(h16, Bp3, sup16);
    spmm_bf16<true><<<g_spmm, blk, 0, stream>>>(row_ptr, edges_s, sup16, b3, h16);
    // ---- layer 4 ----
    gemm_w4<<<(NN + 255) / 256, blk, 0, stream>>>(h16, W4, sup6, NN);
    spmm6<<<(NN * 16 + 255) / 256, blk, 0, stream>>>(row_ptr, edges_s, sup6, b4, out);
}

// Round 13
// 413.778 us; speedup vs baseline: 1.2324x; 1.0115x over previous
//
#include <hip/hip_runtime.h>
#include <cstdint>

constexpr int NN = 100000;   // nodes
constexpr int NE = 1600000;  // edges
constexpr int FIN = 512;
constexpr int HID = 128;
constexpr int NCLS = 6;
constexpr int EPAD = NE + 3 * NN;   // upper bound on pad-to-4 CSR edges

typedef __attribute__((ext_vector_type(8))) short short8v;  // 8 bf16 (4 VGPR)
typedef __attribute__((ext_vector_type(4))) float f32x4;

constexpr float WINV = 1.0f / 32767.0f;

__device__ __forceinline__ unsigned short f2bf(float f) {
    uint32_t u = __float_as_uint(f);
    uint32_t r = u + 0x7FFFu + ((u >> 16) & 1u);   // round-to-nearest-even
    return (unsigned short)(r >> 16);
}
__device__ __forceinline__ float bflo(uint32_t u) { return __uint_as_float(u << 16); }
__device__ __forceinline__ float bfhi(uint32_t u) { return __uint_as_float(u & 0xffff0000u); }

// async global -> LDS, 16B per lane; lds dest must be wave-uniform base
__device__ __forceinline__ void gl_lds16(const void* g, void* l) {
    __builtin_amdgcn_global_load_lds(
        (const __attribute__((address_space(1))) unsigned int*)(unsigned long long)g,
        (__attribute__((address_space(3))) unsigned int*)(unsigned int)(unsigned long long)l,
        16, 0, 0);
}

// ============ W fp32 -> fragment-ordered bf16 (device body) ================
__device__ __forceinline__ void cvt_body(const float* __restrict__ W,
                                         unsigned short* __restrict__ Bp, int t) {
    const int lane = t & 63;
    const int fi = t >> 6;
    const int n = fi & 7, ks = fi >> 3;
    const int krow = ks * 32 + (lane >> 4) * 8;
    const int col = n * 16 + (lane & 15);
    short8v sv;
    #pragma unroll
    for (int j = 0; j < 8; ++j) sv[j] = (short)f2bf(W[(size_t)(krow + j) * HID + col]);
    *(short8v*)&Bp[(size_t)t * 8] = sv;
}

// ============ GEMM body: C[r][128](bf16) = A[tile,K] @ Bp ==================
// BM=160 rows, 5 waves x 32 rows, KS=32. Per-wave private LDS slices, NO
// barriers. B fragments REGISTER-DOUBLE-BUFFERED one step ahead: per step,
// issue loadB(k+1)+stage(k+1), wait vmcnt(8+NISS) -> drains B(k)+stage(k)
// (issued a full step earlier; latency hidden). MFMA consumes bcur regs.
template<int K, bool ABF>
__device__ __forceinline__ void gemm_body(unsigned char* lds,
                                          const void* __restrict__ Av,
                                          const unsigned short* __restrict__ Bp,
                                          unsigned short* __restrict__ C, int bid) {
    constexpr int BM    = 160;
    constexpr int KS    = 32;
    constexpr int EB    = ABF ? 2 : 4;
    constexpr int ROWB  = KS * EB;           // 64 / 128
    constexpr int SLOTS = ROWB / 16;         // 4 / 8
    constexpr int SMSK  = SLOTS - 1;
    constexpr int CHUNK = BM * ROWB;         // 10240 / 20480
    constexpr int WBYT  = CHUNK / 5;
    constexpr int NISS  = WBYT / 1024;       // 2 / 4
    constexpr int NS    = K / KS;
    constexpr int WAITN = 8 + NISS;          // keep newest {B(k+1), stage(k+1)}

    const int tid  = threadIdx.x;
    const int lane = tid & 63;
    const int wave = tid >> 6;               // 0..4
    const int row0 = bid * BM;
    const int lr   = lane & 15;
    const int kg   = lane >> 4;              // 0..3

    const unsigned char* Ab = (const unsigned char*)Av;
    const size_t rowbytes = (size_t)K * EB;

    auto stage = [&](int bufsel, int ks) {
        const size_t kbyte = (size_t)ks * ROWB;
        #pragma unroll
        for (int i = 0; i < NISS; ++i) {
            const int Lw   = wave * WBYT + i * 1024 + lane * 16;
            const int row  = Lw / ROWB;
            const int slot = (Lw >> 4) & SMSK;
            const int src  = slot ^ (row & SMSK);
            const unsigned char* g = Ab + (size_t)(row0 + row) * rowbytes + kbyte + src * 16;
            void* l = (void*)&lds[bufsel * CHUNK + wave * WBYT + i * 1024];
            gl_lds16(g, l);
        }
    };

    auto loadB = [&](int ks, short8v (&b)[8]) {
        const unsigned short* bb = Bp + ((size_t)ks * 8 * 64 + lane) * 8;
        #pragma unroll
        for (int n = 0; n < 8; ++n)
            b[n] = *reinterpret_cast<const short8v*>(bb + (size_t)n * 64 * 8);
    };

    short8v bcur[8], bnxt[8];
    f32x4 acc[2][8] = {};

    // prologue: B(0) + stage(0), drain fully
    loadB(0, bcur);
    stage(0, 0);
    asm volatile("s_waitcnt vmcnt(0)" ::: "memory");
    __builtin_amdgcn_sched_barrier(0);

    int cur = 0;
    for (int ks = 0; ks < NS; ++ks) {
        if (ks + 1 < NS) {
            loadB(ks + 1, bnxt);               // 8 loads (newest-8 after stage)
            stage(cur ^ 1, ks + 1);            // NISS DMAs (newest)
            if (ks > 0) {
                // drain B(ks)+stage(ks) (issued a full step ago); keep the
                // WAITN just-issued next-step ops in flight.
                asm volatile("s_waitcnt vmcnt(%0)" :: "i"(WAITN) : "memory");
            }
        } else {
            asm volatile("s_waitcnt vmcnt(0)" ::: "memory");
        }
        __builtin_amdgcn_sched_barrier(0);

        const unsigned char* base = &lds[cur * CHUNK];
        const int rA0 = wave * 32 + lr;
        const int rA1 = rA0 + 16;
        const int key = lr & SMSK;

        short8v a0, a1;
        if constexpr (ABF) {
            a0 = *(const short8v*)(base + rA0 * ROWB + ((kg ^ key) * 16));
            a1 = *(const short8v*)(base + rA1 * ROWB + ((kg ^ key) * 16));
        } else {
            const float4 f00 = *(const float4*)(base + rA0 * ROWB + (((2 * kg + 0) ^ key) * 16));
            const float4 f01 = *(const float4*)(base + rA0 * ROWB + (((2 * kg + 1) ^ key) * 16));
            const float4 f10 = *(const float4*)(base + rA1 * ROWB + (((2 * kg + 0) ^ key) * 16));
            const float4 f11 = *(const float4*)(base + rA1 * ROWB + (((2 * kg + 1) ^ key) * 16));
            a0[0] = (short)f2bf(f00.x); a0[1] = (short)f2bf(f00.y);
            a0[2] = (short)f2bf(f00.z); a0[3] = (short)f2bf(f00.w);
            a0[4] = (short)f2bf(f01.x); a0[5] = (short)f2bf(f01.y);
            a0[6] = (short)f2bf(f01.z); a0[7] = (short)f2bf(f01.w);
            a1[0] = (short)f2bf(f10.x); a1[1] = (short)f2bf(f10.y);
            a1[2] = (short)f2bf(f10.z); a1[3] = (short)f2bf(f10.w);
            a1[4] = (short)f2bf(f11.x); a1[5] = (short)f2bf(f11.y);
            a1[6] = (short)f2bf(f11.z); a1[7] = (short)f2bf(f11.w);
        }

        #pragma unroll
        for (int n = 0; n < 8; ++n) {
            acc[0][n] = __builtin_amdgcn_mfma_f32_16x16x32_bf16(a0, bcur[n], acc[0][n], 0, 0, 0);
            acc[1][n] = __builtin_amdgcn_mfma_f32_16x16x32_bf16(a1, bcur[n], acc[1][n], 0, 0, 0);
        }
        if (ks + 1 < NS) {
            #pragma unroll
            for (int n = 0; n < 8; ++n) bcur[n] = bnxt[n];
        }
        cur ^= 1;
    }

    // C/D layout: col = lane&15, row = (lane>>4)*4 + reg   [m89-verified]
    #pragma unroll
    for (int m = 0; m < 2; ++m)
        #pragma unroll
        for (int n = 0; n < 8; ++n)
            #pragma unroll
            for (int i = 0; i < 4; ++i) {
                const int r = row0 + wave * 32 + m * 16 + kg * 4 + i;
                C[(size_t)r * HID + n * 16 + lr] = f2bf(acc[m][n][i]);
            }
}

// ---- standalone GEMM kernel (layers 2/3, bf16 A) --------------------------
__launch_bounds__(320)
__global__ void gemm_lds_bf(const void* __restrict__ Av, const unsigned short* __restrict__ Bp,
                            unsigned short* __restrict__ C) {
    __shared__ __attribute__((aligned(16))) unsigned char lds[2 * 160 * 64];
    gemm_body<HID, true>(lds, Av, Bp, C, blockIdx.x);
}

// ============ scatter / pad device bodies ==================================
__device__ __forceinline__ void scatter_one(int r, int c, float w,
                                            const int* __restrict__ row_ptr,
                                            int* __restrict__ cur,
                                            uint32_t* __restrict__ edges) {
    const int pos = row_ptr[r] + atomicAdd(&cur[r], 1);
    edges[pos] = ((uint32_t)c << 15) | (uint32_t)(w * 32767.0f + 0.5f);
}

// ============ FUSED: hist + cvt_w3 (independent work, one launch) ==========
__global__ void fused_hist_cvt(const int4* __restrict__ erow4, int* __restrict__ cnt,
                               const float* __restrict__ W1, const float* __restrict__ W2,
                               const float* __restrict__ W3,
                               unsigned short* __restrict__ Bp1, unsigned short* __restrict__ Bp2,
                               unsigned short* __restrict__ Bp3) {
    constexpr int NB_HIST = (NE / 4 + 255) / 256;     // 1563
    const int bid = blockIdx.x;
    if (bid < NB_HIST) {
        const int t = bid * 256 + threadIdx.x;
        if (t < NE / 4) {
            const int4 r = erow4[t];
            atomicAdd(&cnt[r.x], 1);
            atomicAdd(&cnt[r.y], 1);
            atomicAdd(&cnt[r.z], 1);
            atomicAdd(&cnt[r.w], 1);
        }
    } else {
        const int t = (bid - NB_HIST) * 256 + threadIdx.x;
        constexpr int T1 = (FIN / 32) * 8 * 64;       // 8192
        constexpr int T2 = (HID / 32) * 8 * 64;       // 2048
        if (t < T1)                cvt_body(W1, Bp1, t);
        else if (t < T1 + T2)      cvt_body(W2, Bp2, t - T1);
        else if (t < T1 + 2 * T2)  cvt_body(W3, Bp3, t - T1 - T2);
    }
}

// ============ FUSED: layer-1 GEMM + scatter + pad ==========================
// pad uses row_cnt (final hist counts) so its slots are DISJOINT from
// scatter's -> safe concurrency. All independent of gemm's outputs.
constexpr int GB_GEMM = NN / 160;                          // 625
constexpr int GB_SCAT = (NE / 4 + 319) / 320;              // 1250
constexpr int GB_PAD  = (NN + 319) / 320;                  // 313

__launch_bounds__(320)
__global__ void fused_l1(const float* __restrict__ x, const unsigned short* __restrict__ Bp1,
                         unsigned short* __restrict__ sup16,
                         const int4* __restrict__ erow4, const int4* __restrict__ ecol4,
                         const float4* __restrict__ ew4,
                         const int* __restrict__ row_ptr, const int* __restrict__ row_cnt,
                         int* __restrict__ cur, uint32_t* __restrict__ edges) {
    __shared__ __attribute__((aligned(16))) unsigned char lds[2 * 160 * 128];
    const int bid = blockIdx.x;
    if (bid < GB_GEMM) {
        gemm_body<FIN, false>(lds, x, Bp1, sup16, bid);
    } else if (bid < GB_GEMM + GB_SCAT) {
        const int t = (bid - GB_GEMM) * 320 + threadIdx.x;
        if (t < NE / 4) {
            const int4 r = erow4[t];
            const int4 c = ecol4[t];
            const float4 w = ew4[t];
            scatter_one(r.x, c.x, w.x, row_ptr, cur, edges);
            scatter_one(r.y, c.y, w.y, row_ptr, cur, edges);
            scatter_one(r.z, c.z, w.z, row_ptr, cur, edges);
            scatter_one(r.w, c.w, w.w, row_ptr, cur, edges);
        }
    } else {
        const int r = (bid - GB_GEMM - GB_SCAT) * 320 + threadIdx.x;
        if (r < NN) {
            const int end = row_ptr[r + 1];
            for (int p = row_ptr[r] + row_cnt[r]; p < end; ++p) edges[p] = 0u;
        }
    }
}

// ---------------- GEMM for W4 [128,6], bf16 H ------------------------------
__global__ void gemm_w4(const unsigned short* __restrict__ H, const float* __restrict__ W,
                        float* __restrict__ S, int M) {
    __shared__ float Ws[HID * NCLS];
    for (int i = threadIdx.x; i < HID * NCLS; i += blockDim.x) Ws[i] = W[i];
    __syncthreads();
    const int r = blockIdx.x * blockDim.x + threadIdx.x;
    if (r >= M) return;
    float acc[NCLS] = {};
    const unsigned short* h = &H[(size_t)r * HID];
    for (int k0 = 0; k0 < HID; k0 += 8) {
        const uint4 hv = *reinterpret_cast<const uint4*>(&h[k0]);
        float hf[8];
        hf[0] = bflo(hv.x); hf[1] = bfhi(hv.x);
        hf[2] = bflo(hv.y); hf[3] = bfhi(hv.y);
        hf[4] = bflo(hv.z); hf[5] = bfhi(hv.z);
        hf[6] = bflo(hv.w); hf[7] = bfhi(hv.w);
        #pragma unroll
        for (int u = 0; u < 8; ++u)
            #pragma unroll
            for (int j = 0; j < NCLS; ++j)
                acc[j] = fmaf(hf[u], Ws[(k0 + u) * NCLS + j], acc[j]);
    }
    #pragma unroll
    for (int j = 0; j < NCLS; ++j) S[(size_t)r * NCLS + j] = acc[j];
}

// ================= scans (pad counts to %4) ================================
__global__ void scan1_k(const int* __restrict__ in, int* __restrict__ out,
                        int* __restrict__ bsum, int n) {
    __shared__ int s[256];
    const int tid = threadIdx.x;
    const int gid = blockIdx.x * 256 + tid;
    const int v = (gid < NN) ? ((in[gid] + 3) & ~3) : 0;
    s[tid] = v;
    __syncthreads();
    for (int off = 1; off < 256; off <<= 1) {
        const int t = (tid >= off) ? s[tid - off] : 0;
        __syncthreads();
        s[tid] += t;
        __syncthreads();
    }
    if (gid < n) out[gid] = s[tid] - v;
    if (tid == 255) bsum[blockIdx.x] = s[255];
}

__global__ void scan2_k(int* __restrict__ bsum, int nb) {
    __shared__ int s[512];
    const int tid = threadIdx.x;
    const int v = (tid < nb) ? bsum[tid] : 0;
    s[tid] = v;
    __syncthreads();
    for (int off = 1; off < 512; off <<= 1) {
        const int t = (tid >= off) ? s[tid - off] : 0;
        __syncthreads();
        s[tid] += t;
        __syncthreads();
    }
    if (tid < nb) bsum[tid] = s[tid] - v;
}

__global__ void scan3_k(int* __restrict__ out, const int* __restrict__ bsum, int n) {
    const int gid = blockIdx.x * 256 + threadIdx.x;
    if (gid < n) out[gid] += bsum[blockIdx.x];
}

// ============ CSR SpMM, F=128, bf16 in/out, 16-deep gather MLP =============
template<bool RELU>
__launch_bounds__(256)
__global__ void spmm_bf16(const int* __restrict__ row_ptr,
                          const uint32_t* __restrict__ edges,
                          const unsigned short* __restrict__ S,
                          const float* __restrict__ bias,
                          unsigned short* __restrict__ out) {
    const int lane = threadIdx.x & 63;
    const int row = blockIdx.x * 4 + (threadIdx.x >> 6);
    if (row >= NN) return;
    const int beg = row_ptr[row];
    const int end = row_ptr[row + 1];
    const int fo = lane * 2;
    float2 a0 = *reinterpret_cast<const float2*>(&bias[fo]);
    float2 a1 = {0.f, 0.f}, a2 = {0.f, 0.f}, a3 = {0.f, 0.f};

    int j = beg;
    for (; j + 16 <= end; j += 16) {
        uint4 e0 = *reinterpret_cast<const uint4*>(edges + j);
        uint4 e1 = *reinterpret_cast<const uint4*>(edges + j + 4);
        uint4 e2 = *reinterpret_cast<const uint4*>(edges + j + 8);
        uint4 e3 = *reinterpret_cast<const uint4*>(edges + j + 12);
        const uint32_t ea[16] = {e0.x, e0.y, e0.z, e0.w, e1.x, e1.y, e1.z, e1.w,
                                 e2.x, e2.y, e2.z, e2.w, e3.x, e3.y, e3.z, e3.w};
        uint32_t s[16];
        #pragma unroll
        for (int q = 0; q < 16; ++q)
            s[q] = *reinterpret_cast<const uint32_t*>(&S[(size_t)(ea[q] >> 15) * HID + fo]);
        #pragma unroll
        for (int q = 0; q < 4; ++q) {
            const float w0 = (float)(ea[q]      & 0x7FFFu) * WINV;
            const float w1 = (float)(ea[q + 4]  & 0x7FFFu) * WINV;
            const float w2 = (float)(ea[q + 8]  & 0x7FFFu) * WINV;
            const float w3 = (float)(ea[q + 12] & 0x7FFFu) * WINV;
            a0.x = fmaf(bflo(s[q]),      w0, a0.x); a0.y = fmaf(bfhi(s[q]),      w0, a0.y);
            a1.x = fmaf(bflo(s[q + 4]),  w1, a1.x); a1.y = fmaf(bfhi(s[q + 4]),  w1, a1.y);
            a2.x = fmaf(bflo(s[q + 8]),  w2, a2.x); a2.y = fmaf(bfhi(s[q + 8]),  w2, a2.y);
            a3.x = fmaf(bflo(s[q + 12]), w3, a3.x); a3.y = fmaf(bfhi(s[q + 12]), w3, a3.y);
        }
    }
    for (; j < end; j += 4) {
        const uint4 e = *reinterpret_cast<const uint4*>(edges + j);
        const uint32_t ea[4] = {e.x, e.y, e.z, e.w};
        uint32_t s[4];
        #pragma unroll
        for (int q = 0; q < 4; ++q)
            s[q] = *reinterpret_cast<const uint32_t*>(&S[(size_t)(ea[q] >> 15) * HID + fo]);
        const float w0 = (float)(ea[0] & 0x7FFFu) * WINV;
        const float w1 = (float)(ea[1] & 0x7FFFu) * WINV;
        const float w2 = (float)(ea[2] & 0x7FFFu) * WINV;
        const float w3 = (float)(ea[3] & 0x7FFFu) * WINV;
        a0.x = fmaf(bflo(s[0]), w0, a0.x); a0.y = fmaf(bfhi(s[0]), w0, a0.y);
        a1.x = fmaf(bflo(s[1]), w1, a1.x); a1.y = fmaf(bfhi(s[1]), w1, a1.y);
        a2.x = fmaf(bflo(s[2]), w2, a2.x); a2.y = fmaf(bfhi(s[2]), w2, a2.y);
        a3.x = fmaf(bflo(s[3]), w3, a3.x); a3.y = fmaf(bfhi(s[3]), w3, a3.y);
    }
    float fx = (a0.x + a1.x) + (a2.x + a3.x);
    float fy = (a0.y + a1.y) + (a2.y + a3.y);
    if (RELU) { fx = fmaxf(fx, 0.f); fy = fmaxf(fy, 0.f); }
    const uint32_t o = (uint32_t)f2bf(fx) | ((uint32_t)f2bf(fy) << 16);
    *reinterpret_cast<uint32_t*>(&out[(size_t)row * HID + fo]) = o;
}

// ============ CSR SpMM, F=6, fp32, 16 lanes/row ============================
__launch_bounds__(256)
__global__ void spmm6(const int* __restrict__ row_ptr,
                      const uint32_t* __restrict__ edges,
                      const float* __restrict__ S,
                      const float* __restrict__ bias,
                      float* __restrict__ out) {
    const int t = blockIdx.x * blockDim.x + threadIdx.x;
    const int row = t >> 4;
    const int sl = t & 15;
    if (row >= NN) return;
    const int beg = row_ptr[row];
    const int end = row_ptr[row + 1];
    float acc[NCLS] = {};
    for (int j = beg + sl; j < end; j += 16) {
        const uint32_t e = edges[j];
        const float w = (float)(e & 0x7FFFu) * WINV;
        const float* s = &S[(size_t)(e >> 15) * NCLS];
        #pragma unroll
        for (int k = 0; k < NCLS; ++k) acc[k] = fmaf(s[k], w, acc[k]);
    }
    #pragma unroll
    for (int off = 8; off > 0; off >>= 1)
        #pragma unroll
        for (int k = 0; k < NCLS; ++k) acc[k] += __shfl_xor(acc[k], off, 64);
    if (sl == 0) {
        #pragma unroll
        for (int k = 0; k < NCLS; ++k) out[(size_t)row * NCLS + k] = acc[k] + bias[k];
    }
}

extern "C" void kernel_launch(void* const* d_in, const int* in_sizes, int n_in,
                              void* d_out, int out_size, void* d_ws, size_t ws_size,
                              hipStream_t stream) {
    const float* x    = (const float*)d_in[0];
    const int*   erow = (const int*)d_in[1];
    const int*   ecol = (const int*)d_in[2];
    const float* ew   = (const float*)d_in[3];
    const float* W1 = (const float*)d_in[4];  const float* b1 = (const float*)d_in[5];
    const float* W2 = (const float*)d_in[6];  const float* b2 = (const float*)d_in[7];
    const float* W3 = (const float*)d_in[8];  const float* b3 = (const float*)d_in[9];
    const float* W4 = (const float*)d_in[10]; const float* b4 = (const float*)d_in[11];
    float* out = (float*)d_out;

    // ---- workspace layout ----
    uint32_t*       edges_s = (uint32_t*)d_ws;                      // EPAD*4B
    unsigned short* sup16   = (unsigned short*)(edges_s + EPAD);    // NN*128*2B
    unsigned short* h16     = sup16 + (size_t)NN * HID;             // NN*128*2B
    float*          sup6    = (float*)(h16 + (size_t)NN * HID);     // NN*6*4B
    unsigned short* Bp1     = (unsigned short*)(sup6 + (size_t)NN * NCLS);
    unsigned short* Bp2     = Bp1 + (size_t)FIN * HID;
    unsigned short* Bp3     = Bp2 + (size_t)HID * HID;
    int*            row_ptr = (int*)(Bp3 + (size_t)HID * HID);      // NN+1
    int*            row_cnt = row_ptr + (NN + 1);                   // NN (hist)
    int*            row_cur = row_cnt + NN;                         // NN (scatter cursor)
    int*            bsum    = row_cur + NN;                         // 512

    const dim3 blk(256);
    const int  NB = (NN + 1 + 255) / 256;
    constexpr int NB_HIST = (NE / 4 + 255) / 256;                   // 1563
    constexpr int NB_CVT  = 12288 / 256;                            // 48

    // ---- memset cnt+cur, then fused hist + weight-convert ----
    hipMemsetAsync(row_cnt, 0, (size_t)2 * NN * sizeof(int), stream);
    fused_hist_cvt<<<NB_HIST + NB_CVT, blk, 0, stream>>>(
        (const int4*)erow, row_cnt, W1, W2, W3, Bp1, Bp2, Bp3);

    // ---- scan (pad counts to %4) ----
    scan1_k<<<NB, blk, 0, stream>>>(row_cnt, row_ptr, bsum, NN + 1);
    scan2_k<<<1, 512, 0, stream>>>(bsum, NB);
    scan3_k<<<NB, blk, 0, stream>>>(row_ptr, bsum, NN + 1);

    // ---- FUSED layer-1 GEMM + edge scatter + pad (disjoint slots) ----
    fused_l1<<<GB_GEMM + GB_SCAT + GB_PAD, dim3(320), 0, stream>>>(
        x, Bp1, sup16, (const int4*)erow, (const int4*)ecol, (const float4*)ew,
        row_ptr, row_cnt, row_cur, edges_s);

    const int g_spmm = NN / 4;
    // ---- layer 1 aggregate ----
    spmm_bf16<true><<<g_spmm, blk, 0, stream>>>(row_ptr, edges_s, sup16, b1, h16);
    // ---- layer 2 ----
    gemm_lds_bf<<<GB_GEMM, dim3(320), 0, stream>>>(h16, Bp2, sup16);
    spmm_bf16<true><<<g_spmm, blk, 0, stream>>>(row_ptr, edges_s, sup16, b2, h16);
    // ---- layer 3 ----
    gemm_lds_bf<<<GB_GEMM, dim3(320), 0, stream>>>(h16, Bp3, sup16);
    spmm_bf16<true><<<g_spmm, blk, 0, stream>>>(row_ptr, edges_s, sup16, b3, h16);
    // ---- layer 4 ----
    gemm_w4<<<(NN + 255) / 256, blk, 0, stream>>>(h16, W4, sup6, NN);
    spmm6<<<(NN * 16 + 255) / 256, blk, 0, stream>>>(row_ptr, edges_s, sup6, b4, out);
}